// Round 8
// baseline (404.880 us; speedup 1.0000x reference)
//
#include <hip/hip_runtime.h>

typedef __attribute__((ext_vector_type(8))) short bf16x8;
typedef __attribute__((ext_vector_type(4))) float f32x4;
typedef __attribute__((ext_vector_type(2))) unsigned int u32x2;
typedef __attribute__((ext_vector_type(4))) unsigned int u32x4;

#define LOG2E  1.442695040888963f
#define LOG2E2 2.885390081777927f

__device__ __forceinline__ unsigned cvt_pk_bf16(float lo, float hi){
  unsigned r; asm("v_cvt_pk_bf16_f32 %0, %1, %2" : "=v"(r) : "v"(lo), "v"(hi)); return r;
}
// z already scaled by log2e: sigmoid(x) = rcp(1+2^(-z))
__device__ __forceinline__ float sig_p(float z){
  return __builtin_amdgcn_rcpf(1.f + __builtin_amdgcn_exp2f(-z));
}
// z already scaled by 2*log2e: tanh(x) = 1 - 2*rcp(1+2^z)
__device__ __forceinline__ float tanhg_p(float z){
  return 1.f - 2.f*__builtin_amdgcn_rcpf(1.f + __builtin_amdgcn_exp2f(z));
}
// natural-domain tanh (for c)
__device__ __forceinline__ float tanh_f(float x){
  return 1.f - 2.f*__builtin_amdgcn_rcpf(1.f + __builtin_amdgcn_exp2f(LOG2E2*x));
}

// ---------------- prologue 1: embproj[dir][tok][m] = (emb[tok]@Wx + b) * gate_scale ------
__global__ void embproj_kernel(const float* __restrict__ emb,
                               const float* __restrict__ Wx_f, const float* __restrict__ b_f,
                               const float* __restrict__ Wx_b, const float* __restrict__ b_b,
                               float* __restrict__ embproj){
  const int blk = blockIdx.x;              // 1024 blocks = 2 dir * 128 tok * 4 chunks
  const int dir = blk >> 9;
  const int tok = (blk >> 2) & 127;
  const int m   = (blk & 3)*256 + threadIdx.x;
  const float* Wx = dir ? Wx_b : Wx_f;
  const float* bb = dir ? b_b  : b_f;
  __shared__ float es[128];
  if (threadIdx.x < 128) es[threadIdx.x] = emb[tok*128 + threadIdx.x];
  __syncthreads();
  float acc = bb[m];
  #pragma unroll 4
  for (int e = 0; e < 128; e++) acc = fmaf(es[e], Wx[e*1024 + m], acc);
  const float s = ((m >> 8) == 2) ? LOG2E2 : LOG2E;   // g-gate gets 2*log2e
  embproj[(dir*128 + tok)*1024 + m] = acc * s;
}

// ---------------- prologue 2: pack Wh^T into MFMA A-fragment order (bf16), pre-scaled -----
// frag layout: [dir][mf(64)][kb(8)][lane(64)] x 16B; lane: m = mf*16+(l&15),
// k-slot j: k = kb*32 + (l>>4)*4 + (j&3) + 16*(j>>2)   (A and B use the same map)
__global__ void whpack_kernel(const float* __restrict__ Wh_f, const float* __restrict__ Wh_b,
                              u32x4* __restrict__ whpack){
  const int t = blockIdx.x*256 + threadIdx.x;  // 65536 threads
  const int lane = t & 63;
  const int kb   = (t >> 6) & 7;
  const int mf   = (t >> 9) & 63;
  const int dir  = t >> 15;
  const float* Wh = dir ? Wh_b : Wh_f;  // [256 k][1024 m]
  const int m = mf*16 + (lane & 15);
  const int kbase = kb*32 + ((lane >> 4) << 2);
  const float s = ((mf >> 4) == 2) ? LOG2E2 : LOG2E;
  u32x4 o;
  #pragma unroll
  for (int p = 0; p < 4; p++){           // u32 p holds slots j=2p, 2p+1
    const int k0 = kbase + (p & 1)*2 + (p >> 1)*16;
    unsigned pk = cvt_pk_bf16(Wh[k0*1024 + m]*s, Wh[(k0+1)*1024 + m]*s);
    if (p == 0) o.x = pk; else if (p == 1) o.y = pk; else if (p == 2) o.z = pk; else o.w = pk;
  }
  whpack[t] = o;
}

// ---------------- main: persistent LSTM ---------------------------------------------------
// grid 256 = 2 dir * 128 tiles of 16 batch rows. 512 thr = 8 waves (2/SIMD, 256 unified regs).
// Wave w owns units [32w,32w+32): frag f=g*2+q -> mf=(f>>1)*16+2w+(f&1).
//   Resident (128 regs): kb0,1,2,4.  Streamed via ONE 32-reg window WgA: kb3 then kb5
//   (loop-invariant L2-hot addresses; next step's kb3 issues during gate phase, stays in
//   flight across the lgkmcnt-only barrier).  kb6,7: LDS, single 4-frag JIT window.
// Peak live regs ~244 < 256 (round-7 spilled at ~290: WRITE_SIZE 32MB -> must return to 12.3).
__global__ __launch_bounds__(512, 2) void lstm_kernel(
    const int* __restrict__ tokens, const float* __restrict__ embproj,
    const u32x4* __restrict__ whpack, float* __restrict__ out)
{
  const int bid = blockIdx.x;
  const int dir = bid >> 7;
  const int r0  = (bid & 127) << 4;   // 16 batch rows
  const int tid = threadIdx.x;
  const int w   = tid >> 6;           // 0..7
  const int l   = tid & 63;
  const int l15 = l & 15;
  const int lg  = l >> 4;

  const float* ep = embproj + dir*131072;     // [128 tok][1024 m]
  const u32x4* wp = whpack + dir*32768;

  __shared__ __align__(16) unsigned hbuf[2][8][64][4];   // 16 KB h double-buffer (B-frag)
  __shared__ __align__(16) u32x4 wlds[8][8][2][64];      // 128 KB: [w][f][kb-6][lane]
  __shared__ int ts[16][132];                            // tokens, padded

  for (int i = tid; i < 2048; i += 512)
    ts[i >> 7][i & 127] = tokens[(r0 + (i >> 7))*128 + (i & 127)];
  for (int i = tid; i < 4096; i += 512) (&hbuf[0][0][0][0])[i] = 0u;
  #pragma unroll
  for (int f = 0; f < 8; f++)
    #pragma unroll
    for (int kbh = 0; kbh < 2; kbh++)
      wlds[w][f][kbh][l] = wp[(((f >> 1)*16 + 2*w + (f & 1))*8 + 6 + kbh)*64 + l];

  // resident weight frags kb0,1,2,4 (32 frags = 128 regs, loaded once)
  bf16x8 Wr[8][4];   // [f][j] j=0..2 -> kb j ; j=3 -> kb4
  #pragma unroll
  for (int f = 0; f < 8; f++){
    #pragma unroll
    for (int j = 0; j < 3; j++)
      Wr[f][j] = *(const bf16x8*)&wp[(((f >> 1)*16 + 2*w + (f & 1))*8 + j)*64 + l];
    Wr[f][3] = *(const bf16x8*)&wp[(((f >> 1)*16 + 2*w + (f & 1))*8 + 4)*64 + l];
  }
  __syncthreads();

  f32x4 c4[2] = {{0.f,0.f,0.f,0.f},{0.f,0.f,0.f,0.f}};  // c for (b=r0+l15, u=32w+16q+lg*4+r)

  // prologue: xz(0) -> acc (C-init); WgA <- kb3
  f32x4 acc[8];   // f = g*2+q
  {
    const int tok0 = ts[l15][dir ? 127 : 0];
    const float* gp = ep + tok0*1024 + 32*w + lg*4;
    #pragma unroll
    for (int f = 0; f < 8; f++)
      acc[f] = *(const f32x4*)(gp + (f >> 1)*256 + (f & 1)*16);
  }
  bf16x8 WgA[8];
  #pragma unroll
  for (int f = 0; f < 8; f++)
    WgA[f] = *(const bf16x8*)&wp[(((f >> 1)*16 + 2*w + (f & 1))*8 + 3)*64 + l];

  for (int t = 0; t < 128; t++){
    const int tn    = (t < 127) ? t + 1 : 127;
    const int tok_n = ts[l15][dir ? (127 - tn) : tn];
    const int rb = t & 1;

    bf16x8 B0 = *(const bf16x8*)&hbuf[rb][0][l][0];
    bf16x8 B1 = *(const bf16x8*)&hbuf[rb][1][l][0];
    bf16x8 B2 = *(const bf16x8*)&hbuf[rb][2][l][0];
    #pragma unroll
    for (int f = 0; f < 8; f++)    // kb0
      acc[f] = __builtin_amdgcn_mfma_f32_16x16x32_bf16(Wr[f][0], B0, acc[f], 0, 0, 0);

    bf16x8 B3 = *(const bf16x8*)&hbuf[rb][3][l][0];
    #pragma unroll
    for (int f = 0; f < 8; f++)    // kb1
      acc[f] = __builtin_amdgcn_mfma_f32_16x16x32_bf16(Wr[f][1], B1, acc[f], 0, 0, 0);

    bf16x8 B4 = *(const bf16x8*)&hbuf[rb][4][l][0];
    #pragma unroll
    for (int f = 0; f < 8; f++)    // kb2
      acc[f] = __builtin_amdgcn_mfma_f32_16x16x32_bf16(Wr[f][2], B2, acc[f], 0, 0, 0);

    bf16x8 B6 = *(const bf16x8*)&hbuf[rb][6][l][0];
    #pragma unroll
    for (int f = 0; f < 8; f++)    // kb3 (streamed window, preloaded last step)
      acc[f] = __builtin_amdgcn_mfma_f32_16x16x32_bf16(WgA[f], B3, acc[f], 0, 0, 0);

    // reload window: kb5 (consumed 4 groups later)
    #pragma unroll
    for (int f = 0; f < 8; f++)
      WgA[f] = *(const bf16x8*)&wp[(((f >> 1)*16 + 2*w + (f & 1))*8 + 5)*64 + l];

    bf16x8 B7 = *(const bf16x8*)&hbuf[rb][7][l][0];
    #pragma unroll
    for (int f = 0; f < 8; f++)    // kb4 (resident)
      acc[f] = __builtin_amdgcn_mfma_f32_16x16x32_bf16(Wr[f][3], B4, acc[f], 0, 0, 0);

    bf16x8 B5 = *(const bf16x8*)&hbuf[rb][5][l][0];
    // kb6 (LDS, 4-frag JIT window)
    {
      bf16x8 Wl[4];
      #pragma unroll
      for (int j = 0; j < 4; j++) Wl[j] = *(const bf16x8*)&wlds[w][j][0][l];
      #pragma unroll
      for (int f = 0; f < 4; f++)
        acc[f] = __builtin_amdgcn_mfma_f32_16x16x32_bf16(Wl[f], B6, acc[f], 0, 0, 0);
      #pragma unroll
      for (int j = 0; j < 4; j++) Wl[j] = *(const bf16x8*)&wlds[w][4 + j][0][l];
      #pragma unroll
      for (int f = 4; f < 8; f++)
        acc[f] = __builtin_amdgcn_mfma_f32_16x16x32_bf16(Wl[f - 4], B6, acc[f], 0, 0, 0);
    }
    // kb7 (LDS, 4-frag JIT window)
    {
      bf16x8 Wl[4];
      #pragma unroll
      for (int j = 0; j < 4; j++) Wl[j] = *(const bf16x8*)&wlds[w][j][1][l];
      #pragma unroll
      for (int f = 0; f < 4; f++)
        acc[f] = __builtin_amdgcn_mfma_f32_16x16x32_bf16(Wl[f], B7, acc[f], 0, 0, 0);
      #pragma unroll
      for (int j = 0; j < 4; j++) Wl[j] = *(const bf16x8*)&wlds[w][4 + j][1][l];
      #pragma unroll
      for (int f = 4; f < 8; f++)
        acc[f] = __builtin_amdgcn_mfma_f32_16x16x32_bf16(Wl[f - 4], B7, acc[f], 0, 0, 0);
    }
    #pragma unroll
    for (int f = 0; f < 8; f++)    // kb5 (streamed window)
      acc[f] = __builtin_amdgcn_mfma_f32_16x16x32_bf16(WgA[f], B5, acc[f], 0, 0, 0);

    // reload window for next step: kb3 (in flight across the barrier — no vmcnt drain)
    #pragma unroll
    for (int f = 0; f < 8; f++)
      WgA[f] = *(const bf16x8*)&wp[(((f >> 1)*16 + 2*w + (f & 1))*8 + 3)*64 + l];

    // gates; xz(t+1) prefetch drops into freed acc regs; h -> hbuf frag kb=w
    const float* gpn = ep + tok_n*1024 + 32*w + lg*4;
    u32x4 pk;
    #pragma unroll
    for (int q = 0; q < 2; q++){
      const f32x4 ai = acc[0 + q], af = acc[2 + q], ag = acc[4 + q], ao = acc[6 + q];
      acc[0 + q] = *(const f32x4*)(gpn + 0*256 + q*16);   // xz(t+1) C-init
      acc[2 + q] = *(const f32x4*)(gpn + 1*256 + q*16);
      acc[4 + q] = *(const f32x4*)(gpn + 2*256 + q*16);
      acc[6 + q] = *(const f32x4*)(gpn + 3*256 + q*16);
      f32x4 cn, hn;
      #pragma unroll
      for (int r = 0; r < 4; r++){
        const float cc = sig_p(af[r])*c4[q][r] + sig_p(ai[r])*tanhg_p(ag[r]);
        cn[r] = cc;
        hn[r] = sig_p(ao[r])*tanh_f(cc);
      }
      c4[q] = cn;
      if (q == 0){ pk.x = cvt_pk_bf16(hn[0], hn[1]); pk.y = cvt_pk_bf16(hn[2], hn[3]); }
      else       { pk.z = cvt_pk_bf16(hn[0], hn[1]); pk.w = cvt_pk_bf16(hn[2], hn[3]); }
      if (t == 127){   // final h -> outputs (uniform branch)
        const int b  = r0 + l15;
        const int u0 = 32*w + 16*q + lg*4;
        *(f32x4*)(out + b*512 + dir*256 + u0)               = hn;
        *(f32x4*)(out + 1048576 + dir*1048576 + b*256 + u0) = hn;
      }
    }
    *(u32x4*)&hbuf[rb ^ 1][w][l][0] = pk;
    // T4 barrier: drain LDS only (own reads+write), leave global loads in flight
    asm volatile("s_waitcnt lgkmcnt(0)" ::: "memory");
    __builtin_amdgcn_s_barrier();
    __builtin_amdgcn_sched_barrier(0);
  }

  // final c -> outputs
  #pragma unroll
  for (int q = 0; q < 2; q++){
    const int b  = r0 + l15;
    const int u0 = 32*w + 16*q + lg*4;
    *(f32x4*)(out + 1572864 + dir*1048576 + b*256 + u0) = c4[q];
  }
}

extern "C" void kernel_launch(void* const* d_in, const int* in_sizes, int n_in,
                              void* d_out, int out_size, void* d_ws, size_t ws_size,
                              hipStream_t stream){
  const int*   tokens = (const int*)  d_in[0];
  const float* emb    = (const float*)d_in[1];
  const float* Wx_f   = (const float*)d_in[2];
  const float* Wh_f   = (const float*)d_in[3];
  const float* b_f    = (const float*)d_in[4];
  const float* Wx_b   = (const float*)d_in[5];
  const float* Wh_b   = (const float*)d_in[6];
  const float* b_b    = (const float*)d_in[7];
  float* out = (float*)d_out;

  // ws: embproj 2*128*1024 f32 (1 MB) | whpack 2*64*8*64 frags * 16B (1 MB)
  float*  embproj = (float*)d_ws;
  u32x4*  whpack  = (u32x4*)(embproj + 262144);

  embproj_kernel<<<1024, 256, 0, stream>>>(emb, Wx_f, b_f, Wx_b, b_b, embproj);
  whpack_kernel<<<256, 256, 0, stream>>>(Wh_f, Wh_b, whpack);
  lstm_kernel<<<256, 512, 0, stream>>>(tokens, embproj, whpack, out);
}